// Round 1
// 1858.558 us; speedup vs baseline: 1.0320x; 1.0320x over previous
//
#include <hip/hip_runtime.h>
#include <cstdint>

typedef _Float16 f16;
typedef _Float16 f16x8 __attribute__((ext_vector_type(8)));
typedef _Float16 f16x4 __attribute__((ext_vector_type(4)));
typedef float    f32x4 __attribute__((ext_vector_type(4)));

#define DIMN 1024
#define BATCH 32768
#define NLAYERS 18
#define NBLOCKS 6

// ---- async global->LDS, 16B per lane ----
__device__ __forceinline__ void gl2lds16(const f16* g, const f16* l) {
    auto gp = (const __attribute__((address_space(1))) unsigned int*)(uintptr_t)g;
    auto lp = (__attribute__((address_space(3))) unsigned int*)(uintptr_t)l;
    __builtin_amdgcn_global_load_lds(gp, lp, 16, 0, 0);
}

// ---- convert fp32 x -> fp16 ----
__global__ void cvt_kernel(const float* __restrict__ x, f16* __restrict__ o) {
    int i = (blockIdx.x * 256 + threadIdx.x) * 4;
    float4 v = *(const float4*)&x[i];
    f16x4 r;
    r[0] = (f16)v.x; r[1] = (f16)v.y; r[2] = (f16)v.z; r[3] = (f16)v.w;
    *(f16x4*)&o[i] = r;
}

// ---- W_eff = dequant(int4, group-16 scales) + lb@la, fp16 output ----
__global__ __launch_bounds__(256) void prep_w_kernel(
        const int* __restrict__ qw, const float* __restrict__ sc,
        const float* __restrict__ la, const float* __restrict__ lb,
        f16* __restrict__ W) {
    int b = blockIdx.x;
    int li = b >> 7;
    int og = (b & 127) << 3;  // first of 8 rows
    __shared__ float lbs[8][32];
    int tid = threadIdx.x;
    lbs[tid >> 5][tid & 31] = lb[((size_t)li * 1024 + og + (tid >> 5)) * 32 + (tid & 31)];
    __syncthreads();

    int i0 = tid * 4;  // 4 cols per thread
    const float* laL = la + (size_t)li * 32 * 1024;
    float acc[8][4] = {};
    for (int r = 0; r < 32; ++r) {
        float4 lav = *(const float4*)&laL[r * 1024 + i0];
#pragma unroll
        for (int q = 0; q < 8; ++q) {
            float wv = lbs[q][r];
            acc[q][0] += wv * lav.x; acc[q][1] += wv * lav.y;
            acc[q][2] += wv * lav.z; acc[q][3] += wv * lav.w;
        }
    }
#pragma unroll
    for (int q = 0; q < 8; ++q) {
        size_t row = (size_t)li * 1024 + og + q;
        size_t rowbase = row * 1024;
        int4 code = *(const int4*)&qw[rowbase + i0];
        float scale = sc[row * 64 + (i0 >> 4)];
        f16x4 o;
        o[0] = (f16)((float)code.x * scale + acc[q][0]);
        o[1] = (f16)((float)code.y * scale + acc[q][1]);
        o[2] = (f16)((float)code.z * scale + acc[q][2]);
        o[3] = (f16)((float)code.w * scale + acc[q][3]);
        *(f16x4*)&W[rowbase + i0] = o;
    }
}

// ---- main GEMM: C[M,1024] = A[M,1024] @ W^T + bias, optional relu, fp16 out ----
// BM=BN=256, BK=32, 512 threads (8 waves, 2x4), wave tile 128x64 (8x4 frags).
// 4-deep K-tile LDS pipeline (4 x 32KB), counted vmcnt(8), one raw barrier per
// K-tile, T2 XOR swizzle (pre-swizzled global source, swizzled ds_read),
// T5 setprio around MFMA cluster.
__global__ __launch_bounds__(512, 2) void gemm_kernel(
        const f16* __restrict__ A, const f16* __restrict__ W,
        const float* __restrict__ bias, f16* __restrict__ C, int relu) {
    __shared__ __align__(16) char smem[131072];  // 4 bufs x (A 16KB + B 16KB)

    int tid = threadIdx.x;
    int l = tid & 63, w = tid >> 6;
    int wm = w >> 2, wn = w & 3;

    // XCD-bijective swizzle: 512 wgs -> 64/XCD; 4 n-tiles of an m-tile adjacent
    int hb = blockIdx.x;
    int xcd = hb & 7, idx = hb >> 3;
    int mt = xcd * 16 + (idx >> 2);
    int nt = idx & 3;
    int bm = mt * 256, bn = nt * 256;

    // ---- staging setup: per K-tile each thread issues 4x16B (A j=0/1, B j=0/1)
    // LDS dest is linear: pos = j*512 + tid -> row = j*128 + tid>>2, slot = tid&3.
    // Pre-swizzle source slot: s_src = s_phys ^ swz(row), swz(r) = (r>>1)&3.
    int ss = ((tid & 3) ^ ((tid >> 3) & 3)) * 8;  // f16 offset within 32-wide K
    const f16* Ag0 = A + (size_t)(bm + (tid >> 2)) * DIMN + ss;
    const f16* Ag1 = Ag0 + (size_t)128 * DIMN;
    const f16* Bg0 = W + (size_t)(bn + (tid >> 2)) * DIMN + ss;
    const f16* Bg1 = Bg0 + (size_t)128 * DIMN;
    int ldst = tid * 16;  // LDS byte offset for j=0; j=1 at +8192

    // ---- fragment read addresses (swizzled): row r at byte r*64, slot^swz(r)
    int lr = l & 15;
    int slot = ((l >> 4) ^ (lr >> 1)) & 3;           // swz(r) invariant in m*16
    int byteA = (wm * 128 + lr) * 64 + slot * 16;
    int byteB = (wn * 64 + lr) * 64 + slot * 16 + 16384;

    f32x4 acc[8][4] = {};

    // ---- prologue: stage K-tiles 0,1,2 (12 loads/thread) ----
#pragma unroll
    for (int p = 0; p < 3; ++p) {
        char* bse = smem + p * 32768;
        gl2lds16(Ag0 + p * 32, (const f16*)(bse + ldst));
        gl2lds16(Ag1 + p * 32, (const f16*)(bse + 8192 + ldst));
        gl2lds16(Bg0 + p * 32, (const f16*)(bse + 16384 + ldst));
        gl2lds16(Bg1 + p * 32, (const f16*)(bse + 24576 + ldst));
    }
    // allow tiles 1,2 in flight (8 loads); tile 0 landed for every wave
    asm volatile("s_waitcnt vmcnt(8)" ::: "memory");
    __builtin_amdgcn_s_barrier();
    asm volatile("" ::: "memory");

    // ---- main loop: 32 K-tiles ----
    for (int kt = 0; kt < 32; ++kt) {
        // prefetch K-tile kt+3 (wrapped tail stages into a dead buffer: safe,
        // keeps the vmcnt ledger uniform)
        int kp = (kt + 3) & 31;
        char* bse = smem + ((kt + 3) & 3) * 32768;
        gl2lds16(Ag0 + kp * 32, (const f16*)(bse + ldst));
        gl2lds16(Ag1 + kp * 32, (const f16*)(bse + 8192 + ldst));
        gl2lds16(Bg0 + kp * 32, (const f16*)(bse + 16384 + ldst));
        gl2lds16(Bg1 + kp * 32, (const f16*)(bse + 24576 + ldst));

        const char* buf = smem + (kt & 3) * 32768;
        f16x8 af[8], bf[4];
#pragma unroll
        for (int m = 0; m < 8; ++m)
            af[m] = *(const f16x8*)(buf + byteA + m * 1024);
#pragma unroll
        for (int n = 0; n < 4; ++n)
            bf[n] = *(const f16x8*)(buf + byteB + n * 1024);

        __builtin_amdgcn_s_setprio(1);
#pragma unroll
        for (int m = 0; m < 8; ++m)
#pragma unroll
            for (int n = 0; n < 4; ++n)
                acc[m][n] = __builtin_amdgcn_mfma_f32_16x16x32_f16(
                    af[m], bf[n], acc[m][n], 0, 0, 0);
        __builtin_amdgcn_s_setprio(0);

        // counted wait: tiles kt+2, kt+3 (8 loads) may stay in flight across
        // the barrier; everything older (incl. tile kt+1) has landed.
        asm volatile("s_waitcnt vmcnt(8)" ::: "memory");
        __builtin_amdgcn_s_barrier();
        asm volatile("" ::: "memory");
    }

    // ---- epilogue: bias+relu, pack fp16 via LDS (half-tile at a time), store
    __syncthreads();  // full drain; all LDS buffers dead
    f16* Cs = (f16*)smem;
    const int LDC2 = 264;  // f16 stride; 528B row, 16B-aligned
    int gc = wn * 64 + lr;
    float bsv[4];
#pragma unroll
    for (int j = 0; j < 4; ++j) bsv[j] = bias[bn + gc + j * 16];
    int r0 = (l >> 4) * 4;
    int srow = tid >> 5, sc8 = (tid & 31) * 8;
#pragma unroll
    for (int half = 0; half < 2; ++half) {
        if (wm == half) {
#pragma unroll
            for (int m = 0; m < 8; ++m)
#pragma unroll
                for (int j = 0; j < 4; ++j)
#pragma unroll
                    for (int r = 0; r < 4; ++r) {
                        float v = acc[m][j][r] + bsv[j];
                        if (relu) v = fmaxf(v, 0.f);
                        Cs[(m * 16 + r0 + r) * LDC2 + gc + j * 16] = (f16)v;
                    }
        }
        __syncthreads();
#pragma unroll
        for (int it = 0; it < 8; ++it) {
            int row = srow + it * 16;
            f16x8 val = *(const f16x8*)&Cs[row * LDC2 + sc8];
            *(f16x8*)&C[(size_t)(bm + half * 128 + row) * DIMN + bn + sc8] = val;
        }
        if (half == 0) __syncthreads();
    }
}

// ---- residual + layernorm (mode 0) or final residual fp32 out (mode 1) ----
__global__ void res_ln_kernel(const f16* __restrict__ y, f16* __restrict__ h,
                              const float* __restrict__ g, const float* __restrict__ b,
                              float* __restrict__ outF, int mode) {
    int row = blockIdx.x;
    int tid = threadIdx.x;
    int c0 = tid * 4;
    const f16* yr = y + (size_t)row * DIMN;
    f16* hr = h + (size_t)row * DIMN;

    f16x4 yv = *(const f16x4*)&yr[c0];
    f16x4 hv = *(const f16x4*)&hr[c0];
    float v[4];
    float s = 0.f, sq = 0.f;
#pragma unroll
    for (int i = 0; i < 4; ++i) {
        v[i] = (float)yv[i] + (float)hv[i];
        s += v[i]; sq += v[i] * v[i];
    }
#pragma unroll
    for (int o = 32; o > 0; o >>= 1) {
        s += __shfl_xor(s, o);
        sq += __shfl_xor(sq, o);
    }
    __shared__ float red[8];
    int wv = tid >> 6, ln = tid & 63;
    if (ln == 0) { red[wv] = s; red[4 + wv] = sq; }
    __syncthreads();
    float S1 = red[0] + red[1] + red[2] + red[3];
    float S2 = red[4] + red[5] + red[6] + red[7];
    float mu = S1 * (1.f / 1024.f);
    float var = S2 * (1.f / 1024.f) - mu * mu;
    float rs = rsqrtf(var + 1e-5f);

    if (mode == 0) {
        float4 gv = *(const float4*)&g[c0];
        float4 bv = *(const float4*)&b[c0];
        f16x4 outv;
        outv[0] = (f16)((v[0] - mu) * rs * gv.x + bv.x);
        outv[1] = (f16)((v[1] - mu) * rs * gv.y + bv.y);
        outv[2] = (f16)((v[2] - mu) * rs * gv.z + bv.z);
        outv[3] = (f16)((v[3] - mu) * rs * gv.w + bv.w);
        *(f16x4*)&hr[c0] = outv;
    } else {
        float4 ov;
        ov.x = v[0]; ov.y = v[1]; ov.z = v[2]; ov.w = v[3];
        *(float4*)&outF[(size_t)row * DIMN + c0] = ov;
    }
}

extern "C" void kernel_launch(void* const* d_in, const int* in_sizes, int n_in,
                              void* d_out, int out_size, void* d_ws, size_t ws_size,
                              hipStream_t stream) {
    const float* x    = (const float*)d_in[0];
    const int*   qw   = (const int*)d_in[1];
    const float* sc   = (const float*)d_in[2];
    const float* bias = (const float*)d_in[3];
    const float* la   = (const float*)d_in[4];
    const float* lb   = (const float*)d_in[5];
    const float* lng  = (const float*)d_in[6];
    const float* lnb  = (const float*)d_in[7];
    float* out = (float*)d_out;

    char* ws = (char*)d_ws;
    f16* Weff = (f16*)ws;                                   // 37,748,736 B
    f16* H    = (f16*)(ws + (size_t)37748736);              // 67,108,864 B
    f16* P    = (f16*)(ws + (size_t)37748736 + 67108864);   // 67,108,864 B
    f16* Q    = (f16*)d_out;                                // scratch alias (dead before final fp32 write)

    cvt_kernel<<<BATCH * DIMN / (256 * 4), 256, 0, stream>>>(x, H);
    prep_w_kernel<<<NLAYERS * 128, 256, 0, stream>>>(qw, sc, la, lb, Weff);

    for (int blk = 0; blk < NBLOCKS; ++blk) {
        for (int j = 0; j < 3; ++j) {
            int li = blk * 3 + j;
            const f16* in = (j == 0) ? H : ((j == 1) ? P : Q);
            f16* o = (j == 1) ? Q : P;
            gemm_kernel<<<512, 512, 0, stream>>>(
                in, Weff + ((size_t)li << 20), bias + li * 1024, o, (j < 2) ? 1 : 0);
        }
        int lnidx = (blk < 5) ? blk : 4;  // unused in mode 1
        res_ln_kernel<<<BATCH, 256, 0, stream>>>(
            P, H, lng + lnidx * 1024, lnb + lnidx * 1024, out, (blk == 5) ? 1 : 0);
    }
}

// Round 2
// 1773.021 us; speedup vs baseline: 1.0818x; 1.0482x over previous
//
#include <hip/hip_runtime.h>
#include <cstdint>

typedef _Float16 f16;
typedef _Float16 f16x8 __attribute__((ext_vector_type(8)));
typedef _Float16 f16x4 __attribute__((ext_vector_type(4)));
typedef float    f32x4 __attribute__((ext_vector_type(4)));

#define DIMN 1024
#define BATCH 32768
#define NLAYERS 18
#define NBLOCKS 6

// ---- async global->LDS, 16B per lane ----
__device__ __forceinline__ void gl2lds16(const f16* g, const f16* l) {
    auto gp = (const __attribute__((address_space(1))) unsigned int*)(uintptr_t)g;
    auto lp = (__attribute__((address_space(3))) unsigned int*)(uintptr_t)l;
    __builtin_amdgcn_global_load_lds(gp, lp, 16, 0, 0);
}

// ---- convert fp32 x -> fp16 ----
__global__ void cvt_kernel(const float* __restrict__ x, f16* __restrict__ o) {
    int i = (blockIdx.x * 256 + threadIdx.x) * 4;
    float4 v = *(const float4*)&x[i];
    f16x4 r;
    r[0] = (f16)v.x; r[1] = (f16)v.y; r[2] = (f16)v.z; r[3] = (f16)v.w;
    *(f16x4*)&o[i] = r;
}

// ---- W_eff = dequant(int4, group-16 scales) + lb@la, fp16 output ----
__global__ __launch_bounds__(256) void prep_w_kernel(
        const int* __restrict__ qw, const float* __restrict__ sc,
        const float* __restrict__ la, const float* __restrict__ lb,
        f16* __restrict__ W) {
    int b = blockIdx.x;
    int li = b >> 7;
    int og = (b & 127) << 3;  // first of 8 rows
    __shared__ float lbs[8][32];
    int tid = threadIdx.x;
    lbs[tid >> 5][tid & 31] = lb[((size_t)li * 1024 + og + (tid >> 5)) * 32 + (tid & 31)];
    __syncthreads();

    int i0 = tid * 4;  // 4 cols per thread
    const float* laL = la + (size_t)li * 32 * 1024;
    float acc[8][4] = {};
    for (int r = 0; r < 32; ++r) {
        float4 lav = *(const float4*)&laL[r * 1024 + i0];
#pragma unroll
        for (int q = 0; q < 8; ++q) {
            float wv = lbs[q][r];
            acc[q][0] += wv * lav.x; acc[q][1] += wv * lav.y;
            acc[q][2] += wv * lav.z; acc[q][3] += wv * lav.w;
        }
    }
#pragma unroll
    for (int q = 0; q < 8; ++q) {
        size_t row = (size_t)li * 1024 + og + q;
        size_t rowbase = row * 1024;
        int4 code = *(const int4*)&qw[rowbase + i0];
        float scale = sc[row * 64 + (i0 >> 4)];
        f16x4 o;
        o[0] = (f16)((float)code.x * scale + acc[q][0]);
        o[1] = (f16)((float)code.y * scale + acc[q][1]);
        o[2] = (f16)((float)code.z * scale + acc[q][2]);
        o[3] = (f16)((float)code.w * scale + acc[q][3]);
        *(f16x4*)&W[rowbase + i0] = o;
    }
}

// ---- main GEMM: C[M,1024] = A[M,1024] @ W^T + bias, optional relu, fp16 out ----
// m201-style 8-phase schedule: BM=BN=256, BK=64, 512 thr (8 waves 2Mx4N),
// wave tile 128x64 split in 2x2 half-quadrants; LDS = 2 slots x {A:2half,B:2half}
// x 16KB = 128KB. Per phase: ds_reads + 1 half-tile stage + barrier + lgkmcnt(0)
// + 16 MFMA + barrier. vmcnt(4) only at phases 4/8 (counted, never 0 in loop).
__global__ __launch_bounds__(512, 2) void gemm_kernel(
        const f16* __restrict__ A, const f16* __restrict__ W,
        const float* __restrict__ bias, f16* __restrict__ C, int relu) {
    __shared__ __align__(16) char smem[131072];

    int tid = threadIdx.x;
    int l = tid & 63, w = tid >> 6;
    int wm = w >> 2, wn = w & 3;   // wm 0..1, wn 0..3
    int lr = l & 15;

    // XCD-bijective swizzle: 512 wgs -> 64/XCD; 4 n-tiles of an m-tile adjacent
    int hb = blockIdx.x;
    int xcd = hb & 7, idx = hb >> 3;
    int mt = xcd * 16 + (idx >> 2);
    int nt = idx & 3;
    int bm = mt * 256, bn = nt * 256;

    // ---- staging: half-tile = 128 rows x 64 K f16 = 16KB = 2 x 16B per thread.
    // LDS dest linear (global_load_lds); T2 swizzle via pre-swizzled global k:
    // LDS(row, slot) holds global kslot = slot ^ (row&7); row&7 == (tid>>3)&7.
    int kswz = ((tid & 7) ^ ((tid >> 3) & 7)) * 8;
    const f16* pA = A + (size_t)(bm + (tid >> 3)) * 1024 + kswz;
    const f16* pB = W + (size_t)(bn + (tid >> 3)) * 1024 + kswz;
    int ld0 = tid * 16;

#define STG_A(SL, H, KOFF) do { \
    gl2lds16(pA + ((size_t)((H)*128) << 10) + (KOFF), (const f16*)(smem + (SL)*65536 + (H)*16384 + ld0)); \
    gl2lds16(pA + ((size_t)((H)*128+64) << 10) + (KOFF), (const f16*)(smem + (SL)*65536 + (H)*16384 + 8192 + ld0)); \
  } while(0)
#define STG_B(SL, H, KOFF) do { \
    gl2lds16(pB + ((size_t)((H)*128) << 10) + (KOFF), (const f16*)(smem + (SL)*65536 + 32768 + (H)*16384 + ld0)); \
    gl2lds16(pB + ((size_t)((H)*128+64) << 10) + (KOFF), (const f16*)(smem + (SL)*65536 + 32768 + (H)*16384 + 8192 + ld0)); \
  } while(0)

    // ---- fragment read addressing (swizzled): row*128B + (kslot^(row&7))*16
    int baseA = (wm * 64 + lr) * 128;
    int baseB = 32768 + (wn * 32 + lr) * 128;
    int slt0 = (((l >> 4) + 0) ^ (l & 7)) * 16;  // K-slice 0: kslots 0..3
    int slt1 = (((l >> 4) + 4) ^ (l & 7)) * 16;  // K-slice 1: kslots 4..7

    f16x8 af[4][2], bf[2][2];
    f32x4 acc[2][2][4][2] = {};

#define LDA(SL, MH) do { _Pragma("unroll") \
    for (int mf = 0; mf < 4; ++mf) { \
      af[mf][0] = *(const f16x8*)(smem + (SL)*65536 + (MH)*16384 + baseA + mf*2048 + slt0); \
      af[mf][1] = *(const f16x8*)(smem + (SL)*65536 + (MH)*16384 + baseA + mf*2048 + slt1); \
    } } while(0)
#define LDB(SL, NH) do { _Pragma("unroll") \
    for (int nf = 0; nf < 2; ++nf) { \
      bf[nf][0] = *(const f16x8*)(smem + (SL)*65536 + (NH)*16384 + baseB + nf*2048 + slt0); \
      bf[nf][1] = *(const f16x8*)(smem + (SL)*65536 + (NH)*16384 + baseB + nf*2048 + slt1); \
    } } while(0)
#define QMMA(MH, NH) do { _Pragma("unroll") \
    for (int mf = 0; mf < 4; ++mf) { _Pragma("unroll") for (int nf = 0; nf < 2; ++nf) { \
      acc[MH][NH][mf][nf] = __builtin_amdgcn_mfma_f32_16x16x32_f16(af[mf][0], bf[nf][0], acc[MH][NH][mf][nf], 0, 0, 0); \
      acc[MH][NH][mf][nf] = __builtin_amdgcn_mfma_f32_16x16x32_f16(af[mf][1], bf[nf][1], acc[MH][NH][mf][nf], 0, 0, 0); \
    } } } while(0)
#define PH_TAIL do { \
    __builtin_amdgcn_s_barrier(); \
    asm volatile("s_waitcnt lgkmcnt(0)" ::: "memory"); \
    __builtin_amdgcn_sched_barrier(0); \
    __builtin_amdgcn_s_setprio(1); } while(0)
#define PH_END do { \
    __builtin_amdgcn_sched_barrier(0); \
    __builtin_amdgcn_s_setprio(0); \
    __builtin_amdgcn_s_barrier(); } while(0)

    // ---- prologue: tile0 -> slot0 (all 4 halves), tile1 -> s1.B0, s1.A1 ----
    STG_B(0, 0, 0);
    STG_A(0, 1, 0);
    STG_A(0, 0, 0);
    STG_B(0, 1, 0);
    STG_B(1, 0, 64);
    STG_A(1, 1, 64);
    asm volatile("s_waitcnt vmcnt(4)" ::: "memory");  // tile0 landed
    __builtin_amdgcn_s_barrier();

    // ---- main loop: 8 iters, 2 K-tiles (BK=64) per iter ----
#pragma unroll 1
    for (int i = 0; i < 8; ++i) {
        int k1 = (2 * i + 1) * 64;           // tile read this iter p5-p8
        int k2 = ((2 * i + 2) & 15) * 64;    // prefetch targets
        int k3 = ((2 * i + 3) & 15) * 64;
        bool stg = (i < 7);
        // quadrant order per tile: (0,0),(1,0),(1,1),(0,1)
        // p1: read s0.A0,s0.B0 ; stage s1.A0(2i+1)
        LDA(0, 0); LDB(0, 0); STG_A(1, 0, k1);
        PH_TAIL; QMMA(0, 0); PH_END;
        // p2: read s0.A1 (B reuse) ; stage s1.B1(2i+1)
        LDA(0, 1); STG_B(1, 1, k1);
        PH_TAIL; QMMA(1, 0); PH_END;
        // p3: read s0.B1 (A reuse) ; stage s0.B0(2i+2)
        LDB(0, 1); if (stg) STG_B(0, 0, k2);
        PH_TAIL; QMMA(1, 1); PH_END;
        // p4: read s0.A0 (B reuse) ; stage s0.A1(2i+2) ; vmcnt
        LDA(0, 0); if (stg) STG_A(0, 1, k2);
        if (i == 7) asm volatile("s_waitcnt vmcnt(0)" ::: "memory");
        else        asm volatile("s_waitcnt vmcnt(4)" ::: "memory");
        PH_TAIL; QMMA(0, 1); PH_END;
        // p5: read s1.A0,s1.B0 ; stage s0.A0(2i+2)
        LDA(1, 0); LDB(1, 0); if (stg) STG_A(0, 0, k2);
        PH_TAIL; QMMA(0, 0); PH_END;
        // p6: read s1.A1 ; stage s0.B1(2i+2)
        LDA(1, 1); if (stg) STG_B(0, 1, k2);
        PH_TAIL; QMMA(1, 0); PH_END;
        // p7: read s1.B1 ; stage s1.B0(2i+3)
        LDB(1, 1); if (stg) STG_B(1, 0, k3);
        PH_TAIL; QMMA(1, 1); PH_END;
        // p8: read s1.A0 ; stage s1.A1(2i+3) ; vmcnt
        LDA(1, 0); if (stg) STG_A(1, 1, k3);
        asm volatile("s_waitcnt vmcnt(4)" ::: "memory");
        PH_TAIL; QMMA(0, 1); PH_END;
    }

    // ---- epilogue: bias+relu, LDS repack per 128-row half, coalesced stores
    asm volatile("s_waitcnt vmcnt(0)" ::: "memory");
    __syncthreads();
    f16* Cs = (f16*)smem;
    const int LDC2 = 264;
    float bsv[2][2];
#pragma unroll
    for (int nh = 0; nh < 2; ++nh)
#pragma unroll
        for (int nf = 0; nf < 2; ++nf)
            bsv[nh][nf] = bias[bn + nh * 128 + wn * 32 + nf * 16 + lr];
    int r0 = (l >> 4) * 4;
    int c8 = (tid & 31) * 8, rr = tid >> 5;
#pragma unroll
    for (int mh = 0; mh < 2; ++mh) {
#pragma unroll
        for (int mf = 0; mf < 4; ++mf)
#pragma unroll
            for (int nh = 0; nh < 2; ++nh)
#pragma unroll
                for (int nf = 0; nf < 2; ++nf)
#pragma unroll
                    for (int r = 0; r < 4; ++r) {
                        float v = acc[mh][nh][mf][nf][r] + bsv[nh][nf];
                        if (relu) v = fmaxf(v, 0.f);
                        Cs[(wm * 64 + mf * 16 + r0 + r) * LDC2 + nh * 128 + wn * 32 + nf * 16 + lr] = (f16)v;
                    }
        __syncthreads();
#pragma unroll
        for (int it = 0; it < 8; ++it) {
            int row = rr + it * 16;
            f16x8 val = *(const f16x8*)&Cs[row * LDC2 + c8];
            *(f16x8*)&C[(size_t)(bm + mh * 128 + row) * 1024 + bn + c8] = val;
        }
        if (mh == 0) __syncthreads();
    }
}

// ---- residual + layernorm (mode 0) or final residual fp32 out (mode 1) ----
__global__ void res_ln_kernel(const f16* __restrict__ y, f16* __restrict__ h,
                              const float* __restrict__ g, const float* __restrict__ b,
                              float* __restrict__ outF, int mode) {
    int row = blockIdx.x;
    int tid = threadIdx.x;
    int c0 = tid * 4;
    const f16* yr = y + (size_t)row * DIMN;
    f16* hr = h + (size_t)row * DIMN;

    f16x4 yv = *(const f16x4*)&yr[c0];
    f16x4 hv = *(const f16x4*)&hr[c0];
    float v[4];
    float s = 0.f, sq = 0.f;
#pragma unroll
    for (int i = 0; i < 4; ++i) {
        v[i] = (float)yv[i] + (float)hv[i];
        s += v[i]; sq += v[i] * v[i];
    }
#pragma unroll
    for (int o = 32; o > 0; o >>= 1) {
        s += __shfl_xor(s, o);
        sq += __shfl_xor(sq, o);
    }
    __shared__ float red[8];
    int wv = tid >> 6, ln = tid & 63;
    if (ln == 0) { red[wv] = s; red[4 + wv] = sq; }
    __syncthreads();
    float S1 = red[0] + red[1] + red[2] + red[3];
    float S2 = red[4] + red[5] + red[6] + red[7];
    float mu = S1 * (1.f / 1024.f);
    float var = S2 * (1.f / 1024.f) - mu * mu;
    float rs = rsqrtf(var + 1e-5f);

    if (mode == 0) {
        float4 gv = *(const float4*)&g[c0];
        float4 bv = *(const float4*)&b[c0];
        f16x4 outv;
        outv[0] = (f16)((v[0] - mu) * rs * gv.x + bv.x);
        outv[1] = (f16)((v[1] - mu) * rs * gv.y + bv.y);
        outv[2] = (f16)((v[2] - mu) * rs * gv.z + bv.z);
        outv[3] = (f16)((v[3] - mu) * rs * gv.w + bv.w);
        *(f16x4*)&hr[c0] = outv;
    } else {
        float4 ov;
        ov.x = v[0]; ov.y = v[1]; ov.z = v[2]; ov.w = v[3];
        *(float4*)&outF[(size_t)row * DIMN + c0] = ov;
    }
}

extern "C" void kernel_launch(void* const* d_in, const int* in_sizes, int n_in,
                              void* d_out, int out_size, void* d_ws, size_t ws_size,
                              hipStream_t stream) {
    const float* x    = (const float*)d_in[0];
    const int*   qw   = (const int*)d_in[1];
    const float* sc   = (const float*)d_in[2];
    const float* bias = (const float*)d_in[3];
    const float* la   = (const float*)d_in[4];
    const float* lb   = (const float*)d_in[5];
    const float* lng  = (const float*)d_in[6];
    const float* lnb  = (const float*)d_in[7];
    float* out = (float*)d_out;

    char* ws = (char*)d_ws;
    f16* Weff = (f16*)ws;                                   // 37,748,736 B
    f16* H    = (f16*)(ws + (size_t)37748736);              // 67,108,864 B
    f16* P    = (f16*)(ws + (size_t)37748736 + 67108864);   // 67,108,864 B
    f16* Q    = (f16*)d_out;                                // scratch alias (dead before final fp32 write)

    cvt_kernel<<<BATCH * DIMN / (256 * 4), 256, 0, stream>>>(x, H);
    prep_w_kernel<<<NLAYERS * 128, 256, 0, stream>>>(qw, sc, la, lb, Weff);

    for (int blk = 0; blk < NBLOCKS; ++blk) {
        for (int j = 0; j < 3; ++j) {
            int li = blk * 3 + j;
            const f16* in = (j == 0) ? H : ((j == 1) ? P : Q);
            f16* o = (j == 1) ? Q : P;
            gemm_kernel<<<512, 512, 0, stream>>>(
                in, Weff + ((size_t)li << 20), bias + li * 1024, o, (j < 2) ? 1 : 0);
        }
        int lnidx = (blk < 5) ? blk : 4;  // unused in mode 1
        res_ln_kernel<<<BATCH, 256, 0, stream>>>(
            P, H, lng + lnidx * 1024, lnb + lnidx * 1024, out, (blk == 5) ? 1 : 0);
    }
}

// Round 3
// 1714.201 us; speedup vs baseline: 1.1189x; 1.0343x over previous
//
#include <hip/hip_runtime.h>
#include <cstdint>

typedef _Float16 f16;
typedef _Float16 f16x8 __attribute__((ext_vector_type(8)));
typedef _Float16 f16x4 __attribute__((ext_vector_type(4)));
typedef float    f32x4 __attribute__((ext_vector_type(4)));
typedef float    f32x16 __attribute__((ext_vector_type(16)));

#define DIMN 1024
#define BATCH 32768
#define NLAYERS 18
#define NBLOCKS 6

// ---- async global->LDS, 16B per lane ----
__device__ __forceinline__ void gl2lds16(const f16* g, const f16* l) {
    auto gp = (const __attribute__((address_space(1))) unsigned int*)(uintptr_t)g;
    auto lp = (__attribute__((address_space(3))) unsigned int*)(uintptr_t)l;
    __builtin_amdgcn_global_load_lds(gp, lp, 16, 0, 0);
}

// ---- convert fp32 x -> fp16 ----
__global__ void cvt_kernel(const float* __restrict__ x, f16* __restrict__ o) {
    int i = (blockIdx.x * 256 + threadIdx.x) * 4;
    float4 v = *(const float4*)&x[i];
    f16x4 r;
    r[0] = (f16)v.x; r[1] = (f16)v.y; r[2] = (f16)v.z; r[3] = (f16)v.w;
    *(f16x4*)&o[i] = r;
}

// ---- W_eff = dequant(int4, group-16 scales) + lb@la, fp16 output ----
__global__ __launch_bounds__(256) void prep_w_kernel(
        const int* __restrict__ qw, const float* __restrict__ sc,
        const float* __restrict__ la, const float* __restrict__ lb,
        f16* __restrict__ W) {
    int b = blockIdx.x;
    int li = b >> 7;
    int og = (b & 127) << 3;  // first of 8 rows
    __shared__ float lbs[8][32];
    int tid = threadIdx.x;
    lbs[tid >> 5][tid & 31] = lb[((size_t)li * 1024 + og + (tid >> 5)) * 32 + (tid & 31)];
    __syncthreads();

    int i0 = tid * 4;  // 4 cols per thread
    const float* laL = la + (size_t)li * 32 * 1024;
    float acc[8][4] = {};
    for (int r = 0; r < 32; ++r) {
        float4 lav = *(const float4*)&laL[r * 1024 + i0];
#pragma unroll
        for (int q = 0; q < 8; ++q) {
            float wv = lbs[q][r];
            acc[q][0] += wv * lav.x; acc[q][1] += wv * lav.y;
            acc[q][2] += wv * lav.z; acc[q][3] += wv * lav.w;
        }
    }
#pragma unroll
    for (int q = 0; q < 8; ++q) {
        size_t row = (size_t)li * 1024 + og + q;
        size_t rowbase = row * 1024;
        int4 code = *(const int4*)&qw[rowbase + i0];
        float scale = sc[row * 64 + (i0 >> 4)];
        f16x4 o;
        o[0] = (f16)((float)code.x * scale + acc[q][0]);
        o[1] = (f16)((float)code.y * scale + acc[q][1]);
        o[2] = (f16)((float)code.z * scale + acc[q][2]);
        o[3] = (f16)((float)code.w * scale + acc[q][3]);
        *(f16x4*)&W[rowbase + i0] = o;
    }
}

// ---- main GEMM: C[M,1024] = A[M,1024] @ W^T + bias, optional relu, fp16 out ----
// 32x32x16 MFMA, k-step-16 phases (64 phases), register ping-pong fragments:
// phase P issues ds_reads for P+1, then waits vmcnt(4) lgkmcnt(6) (counted,
// never 0), ONE barrier, 8 MFMA. LDS = 4 slots x 32KB (BK=32). Swizzle:
// phys 16B-slot = kslot ^ ((row>>1)&3), pre-swizzled global source (rule 21).
__global__ __launch_bounds__(512, 2) void gemm_kernel(
        const f16* __restrict__ A, const f16* __restrict__ W,
        const float* __restrict__ bias, f16* __restrict__ C, int relu) {
    __shared__ __align__(16) char smem[131072];

    int tid = threadIdx.x;
    int l = tid & 63, w = tid >> 6;
    int wm = w >> 2, wn = w & 3;   // wave grid 2(M) x 4(N); wave tile 128x64
    int m_l = l & 31;
    int kg = l >> 5;               // k-group within k-step
    int flane = (m_l >> 1) & 3;    // swizzle term: (row>>1)&3 (row = 32q + m_l)

    // XCD-bijective swizzle: 512 wgs -> 64/XCD; 4 n-tiles of an m-tile adjacent
    int hb = blockIdx.x;
    int xcd = hb & 7, idx = hb >> 3;
    int mt = xcd * 16 + (idx >> 2);
    int nt = idx & 3;
    int bm = mt * 256, bn = nt * 256;

    // ---- staging: slot = 32KB {A 256x32k, B 256x32k}; 2 gl2lds per half.
    // thread t -> row t>>2 (+128 for 2nd call), phys slot t&3; source k-slot
    // pre-swizzled: ksrc = (t&3) ^ ((row>>1)&3) = (t&3) ^ ((t>>3)&3).
    int trow = tid >> 2;
    int ksrc = (tid & 3) ^ ((tid >> 3) & 3);
    const f16* pA = A + (size_t)(bm + trow) * 1024 + ksrc * 8;
    const f16* pB = W + (size_t)(bn + trow) * 1024 + ksrc * 8;
    int ld0 = tid * 16;

#define STGA(SL, KT) do { \
    gl2lds16(pA + (KT) * 32, (const f16*)(smem + (SL) * 32768 + ld0)); \
    gl2lds16(pA + 131072 + (KT) * 32, (const f16*)(smem + (SL) * 32768 + 8192 + ld0)); } while (0)
#define STGB(SL, KT) do { \
    gl2lds16(pB + (KT) * 32, (const f16*)(smem + (SL) * 32768 + 16384 + ld0)); \
    gl2lds16(pB + 131072 + (KT) * 32, (const f16*)(smem + (SL) * 32768 + 24576 + ld0)); } while (0)

    // ---- fragment read offsets (swizzled) ----
    int aoff[4], boff[2];
#pragma unroll
    for (int mf = 0; mf < 4; ++mf) aoff[mf] = (wm * 128 + mf * 32 + m_l) * 64;
#pragma unroll
    for (int nf = 0; nf < 2; ++nf) boff[nf] = 16384 + (wn * 64 + nf * 32 + m_l) * 64;
    int slt0 = ((0 + kg) ^ flane) * 16;   // k-step 0 within tile
    int slt1 = ((2 + kg) ^ flane) * 16;   // k-step 1 within tile

    f16x8 aE[4], bE[2], aO[4], bO[2];
    f32x16 acc[4][2] = {};

#define READS(DA, DB, SBASE, SLT) do { _Pragma("unroll") \
    for (int mf = 0; mf < 4; ++mf) DA[mf] = *(const f16x8*)(smem + (SBASE) + aoff[mf] + (SLT)); \
    _Pragma("unroll") \
    for (int nf = 0; nf < 2; ++nf) DB[nf] = *(const f16x8*)(smem + (SBASE) + boff[nf] + (SLT)); } while (0)

    // swapped operands: mfma(bf, af) -> lane holds m = l&31 fixed, 16 n-values
    // n = (reg&3) + 8*(reg>>2) + 4*kg  (4 consecutive n per reg-quad)
#define MMA8(AF, BF) do { _Pragma("unroll") \
    for (int mf = 0; mf < 4; ++mf) { _Pragma("unroll") \
      for (int nf = 0; nf < 2; ++nf) \
        acc[mf][nf] = __builtin_amdgcn_mfma_f32_32x32x16_f16(BF[nf], AF[mf], acc[mf][nf], 0, 0, 0); } } while (0)

#define WAITS do { \
    asm volatile("s_waitcnt vmcnt(4) lgkmcnt(6)" ::: "memory"); \
    __builtin_amdgcn_sched_barrier(0); \
    __builtin_amdgcn_s_barrier(); \
    __builtin_amdgcn_sched_barrier(0); } while (0)

#define PHASES(T4, DT) do { \
    int kp = ((T4) + (DT) + 3) & 31; \
    /* even phase: MFMA(tile, k0) ; read (tile, k1) ; stage A(tile+3) */ \
    READS(aO, bO, ((DT) & 3) * 32768, slt1); \
    STGA(((DT) + 3) & 3, kp); \
    WAITS; \
    __builtin_amdgcn_s_setprio(1); \
    MMA8(aE, bE); \
    __builtin_amdgcn_s_setprio(0); \
    __builtin_amdgcn_sched_barrier(0); \
    /* odd phase: MFMA(tile, k1) ; read (tile+1, k0) ; stage B(tile+3) */ \
    READS(aE, bE, (((DT) + 1) & 3) * 32768, slt0); \
    STGB(((DT) + 3) & 3, kp); \
    WAITS; \
    __builtin_amdgcn_s_setprio(1); \
    MMA8(aO, bO); \
    __builtin_amdgcn_s_setprio(0); \
    __builtin_amdgcn_sched_barrier(0); \
  } while (0)

    // ---- prologue: stage tiles 0,1,2; drain tiles 0,1; preload (t0, k0) ----
    STGA(0, 0); STGB(0, 0);
    STGA(1, 1); STGB(1, 1);
    STGA(2, 2); STGB(2, 2);
    asm volatile("s_waitcnt vmcnt(4)" ::: "memory");
    __builtin_amdgcn_s_barrier();
    READS(aE, bE, 0, slt0);

    // ---- main loop: 32 K-tiles, 2 phases each; slots period-4 ----
#pragma unroll 1
    for (int t4 = 0; t4 < 32; t4 += 4) {
        PHASES(t4, 0);
        PHASES(t4, 1);
        PHASES(t4, 2);
        PHASES(t4, 3);
    }

    // ---- epilogue: bias+relu, pack 4 consecutive cols -> ds_write_b64 ----
    __syncthreads();
    f16* Cs = (f16*)smem;
    float4 bsv[2][4];
#pragma unroll
    for (int nf = 0; nf < 2; ++nf)
#pragma unroll
        for (int g = 0; g < 4; ++g)
            bsv[nf][g] = *(const float4*)&bias[bn + wn * 64 + nf * 32 + g * 8 + kg * 4];

    int c8 = (tid & 31) * 8, rr = tid >> 5;
#pragma unroll
    for (int pass = 0; pass < 2; ++pass) {
        if (wm == pass) {
#pragma unroll
            for (int mf = 0; mf < 4; ++mf) {
                int row = mf * 32 + m_l;
#pragma unroll
                for (int nf = 0; nf < 2; ++nf)
#pragma unroll
                    for (int g = 0; g < 4; ++g) {
                        float4 vb = bsv[nf][g];
                        float v0 = acc[mf][nf][g * 4 + 0] + vb.x;
                        float v1 = acc[mf][nf][g * 4 + 1] + vb.y;
                        float v2 = acc[mf][nf][g * 4 + 2] + vb.z;
                        float v3 = acc[mf][nf][g * 4 + 3] + vb.w;
                        if (relu) {
                            v0 = fmaxf(v0, 0.f); v1 = fmaxf(v1, 0.f);
                            v2 = fmaxf(v2, 0.f); v3 = fmaxf(v3, 0.f);
                        }
                        f16x4 pk;
                        pk[0] = (f16)v0; pk[1] = (f16)v1; pk[2] = (f16)v2; pk[3] = (f16)v3;
                        *(f16x4*)&Cs[row * 264 + wn * 64 + nf * 32 + g * 8 + kg * 4] = pk;
                    }
            }
        }
        __syncthreads();
#pragma unroll
        for (int it = 0; it < 8; ++it) {
            int rowr = rr + it * 16;
            f16x8 val = *(const f16x8*)&Cs[rowr * 264 + c8];
            *(f16x8*)&C[(size_t)(bm + pass * 128 + rowr) * 1024 + bn + c8] = val;
        }
        if (pass == 0) __syncthreads();
    }
}

// ---- residual + layernorm (mode 0) or final residual fp32 out (mode 1) ----
__global__ void res_ln_kernel(const f16* __restrict__ y, f16* __restrict__ h,
                              const float* __restrict__ g, const float* __restrict__ b,
                              float* __restrict__ outF, int mode) {
    int row = blockIdx.x;
    int tid = threadIdx.x;
    int c0 = tid * 4;
    const f16* yr = y + (size_t)row * DIMN;
    f16* hr = h + (size_t)row * DIMN;

    f16x4 yv = *(const f16x4*)&yr[c0];
    f16x4 hv = *(const f16x4*)&hr[c0];
    float v[4];
    float s = 0.f, sq = 0.f;
#pragma unroll
    for (int i = 0; i < 4; ++i) {
        v[i] = (float)yv[i] + (float)hv[i];
        s += v[i]; sq += v[i] * v[i];
    }
#pragma unroll
    for (int o = 32; o > 0; o >>= 1) {
        s += __shfl_xor(s, o);
        sq += __shfl_xor(sq, o);
    }
    __shared__ float red[8];
    int wv = tid >> 6, ln = tid & 63;
    if (ln == 0) { red[wv] = s; red[4 + wv] = sq; }
    __syncthreads();
    float S1 = red[0] + red[1] + red[2] + red[3];
    float S2 = red[4] + red[5] + red[6] + red[7];
    float mu = S1 * (1.f / 1024.f);
    float var = S2 * (1.f / 1024.f) - mu * mu;
    float rs = rsqrtf(var + 1e-5f);

    if (mode == 0) {
        float4 gv = *(const float4*)&g[c0];
        float4 bv = *(const float4*)&b[c0];
        f16x4 outv;
        outv[0] = (f16)((v[0] - mu) * rs * gv.x + bv.x);
        outv[1] = (f16)((v[1] - mu) * rs * gv.y + bv.y);
        outv[2] = (f16)((v[2] - mu) * rs * gv.z + bv.z);
        outv[3] = (f16)((v[3] - mu) * rs * gv.w + bv.w);
        *(f16x4*)&hr[c0] = outv;
    } else {
        float4 ov;
        ov.x = v[0]; ov.y = v[1]; ov.z = v[2]; ov.w = v[3];
        *(float4*)&outF[(size_t)row * DIMN + c0] = ov;
    }
}

extern "C" void kernel_launch(void* const* d_in, const int* in_sizes, int n_in,
                              void* d_out, int out_size, void* d_ws, size_t ws_size,
                              hipStream_t stream) {
    const float* x    = (const float*)d_in[0];
    const int*   qw   = (const int*)d_in[1];
    const float* sc   = (const float*)d_in[2];
    const float* bias = (const float*)d_in[3];
    const float* la   = (const float*)d_in[4];
    const float* lb   = (const float*)d_in[5];
    const float* lng  = (const float*)d_in[6];
    const float* lnb  = (const float*)d_in[7];
    float* out = (float*)d_out;

    char* ws = (char*)d_ws;
    f16* Weff = (f16*)ws;                                   // 37,748,736 B
    f16* H    = (f16*)(ws + (size_t)37748736);              // 67,108,864 B
    f16* P    = (f16*)(ws + (size_t)37748736 + 67108864);   // 67,108,864 B
    f16* Q    = (f16*)d_out;                                // scratch alias (dead before final fp32 write)

    cvt_kernel<<<BATCH * DIMN / (256 * 4), 256, 0, stream>>>(x, H);
    prep_w_kernel<<<NLAYERS * 128, 256, 0, stream>>>(qw, sc, la, lb, Weff);

    for (int blk = 0; blk < NBLOCKS; ++blk) {
        for (int j = 0; j < 3; ++j) {
            int li = blk * 3 + j;
            const f16* in = (j == 0) ? H : ((j == 1) ? P : Q);
            f16* o = (j == 1) ? Q : P;
            gemm_kernel<<<512, 512, 0, stream>>>(
                in, Weff + ((size_t)li << 20), bias + li * 1024, o, (j < 2) ? 1 : 0);
        }
        int lnidx = (blk < 5) ? blk : 4;  // unused in mode 1
        res_ln_kernel<<<BATCH, 256, 0, stream>>>(
            P, H, lng + lnidx * 1024, lnb + lnidx * 1024, out, (blk == 5) ? 1 : 0);
    }
}